// Round 6
// baseline (182.444 us; speedup 1.0000x reference)
//
#include <hip/hip_runtime.h>
#include <cfloat>

// Emu3 VQ-VAE vector quantizer argmin (exact-rounding match to numpy ref):
//   x [9216,4] f32 (channels-last gather from [1,4,4,48,48])
//   e [32768,4] f32
//   out[n] = argmin_k fl( fl(x2+e2) - 2*fl(dot) ), first-min tie semantics.
//
// Round 11 — full occupancy in one generation:
//  - R10 post-mortem: SMEM-resident codebook serialized on scalar-cache
//    latency (5 s_loads per 4 entries, 72cyc VALU cover vs 200+cyc) ->
//    reverted to R8's lanes=entries mapping (best so far, 78.6us).
//  - Coherent R5-R10 story: emitted VALU matches source (~10/eval); real
//    issue util 60-72%; EFFECTIVE resident waves never exceeded 2.8-4.3/SIMD
//    (OccupancyPercent tracked the waves_per_eu max each round). The idle
//    slots are per-wave vmcnt/branch gaps that 3-4 waves can't fill.
//  - Fix: ROWS 12->9. grid = 9216/9 = 1024 blocks = EXACTLY 4 blocks/CU x
//    8 waves = 32 waves/CU = 8 waves/SIMD, all resident, single generation
//    (no tail). e2 amortization 7/9 costs only +2% VALU/eval.
//  - __launch_bounds__(512, 8) pins allocator at <=64 VGPR (live ~58, no
//    spill; R8 chose 64 at ROWS=12 so ROWS=9 has slack).
//  - Arithmetic chain unchanged from validated R8 -> bitwise-same distances.

#define ROWS  9
#define BLOCK 512
#define WAVES (BLOCK / 64)
#define NK    32768
#define EPT   2
#define CHUNK (BLOCK * EPT)   // 1024

__device__ __forceinline__ float rlf(float v) {
    return __builtin_bit_cast(float,
        __builtin_amdgcn_readfirstlane(__builtin_bit_cast(int, v)));
}

__global__ __launch_bounds__(BLOCK, 8)
void vq_argmin_kernel(const float* __restrict__ hs,
                      const float4* __restrict__ cb,
                      int* __restrict__ out)
{
    __shared__ float sRD[WAVES * ROWS];
    __shared__ int   sRI[WAVES * ROWS];

    const int tid = threadIdx.x;
    const int rowbase = blockIdx.x * ROWS;

    // Block-uniform x components -> readfirstlane into SGPRs.
    float sx0[ROWS], sx1[ROWS], sx2[ROWS], sx3[ROWS], sq[ROWS];
    float best[ROWS];
    int   bidx[ROWS];   // stores chunk index m; k = m*BLOCK + tid

    #pragma unroll
    for (int r = 0; r < ROWS; ++r) {
        int n = rowbase + r;
        int t = n / 2304;                 // 2304 = 48*48
        int rem = n - t * 2304;
        const float* ptr = hs + t * 9216 + rem;   // + c*2304 per channel
        float a0 = ptr[0], a1 = ptr[2304], a2 = ptr[4608], a3 = ptr[6912];
        float q = __fadd_rn(__fadd_rn(__fadd_rn(__fmul_rn(a0, a0),
                                                __fmul_rn(a1, a1)),
                                      __fmul_rn(a2, a2)),
                            __fmul_rn(a3, a3));
        sx0[r] = rlf(a0); sx1[r] = rlf(a1);
        sx2[r] = rlf(a2); sx3[r] = rlf(a3);
        sq[r]  = rlf(q);
        best[r] = FLT_MAX; bidx[r] = 0;
    }

    float4 bufA[EPT], bufB[EPT];

    auto load_chunk = [&](float4* buf, int tb) {
        #pragma unroll
        for (int j = 0; j < EPT; ++j) buf[j] = cb[tb + tid + j * BLOCK];
    };
    auto compute_chunk = [&](const float4* buf, int tb) {
        #pragma unroll
        for (int j = 0; j < EPT; ++j) {
            float4 e = buf[j];
            float e2 = __fadd_rn(__fadd_rn(__fadd_rn(__fmul_rn(e.x, e.x),
                                                     __fmul_rn(e.y, e.y)),
                                           __fmul_rn(e.z, e.z)),
                                 __fmul_rn(e.w, e.w));
            int m = tb / BLOCK + j;           // uniform chunk index
            #pragma unroll
            for (int r = 0; r < ROWS; ++r) {
                float dot = __fmul_rn(sx0[r], e.x);
                dot = __fmaf_rn(sx1[r], e.y, dot);
                dot = __fmaf_rn(sx2[r], e.z, dot);
                dot = __fmaf_rn(sx3[r], e.w, dot);
                float t1 = __fadd_rn(sq[r], e2);
                float d  = __fmaf_rn(dot, -2.0f, t1);
                if (d < best[r]) { best[r] = d; bidx[r] = m; }
            }
        }
    };

    // ---- ping-pong K loop: load one buffer while computing the other
    load_chunk(bufA, 0);
    for (int tb = 0; tb < NK; tb += 2 * CHUNK) {
        load_chunk(bufB, tb + CHUNK);
        compute_chunk(bufA, tb);
        int nb = tb + 2 * CHUNK < NK ? tb + 2 * CHUNK : 0;  // last: dummy reload
        load_chunk(bufA, nb);
        compute_chunk(bufB, tb + CHUNK);
    }

    // ---- expand chunk index -> full codebook index, then reduce
    int kk[ROWS];
    #pragma unroll
    for (int r = 0; r < ROWS; ++r) kk[r] = bidx[r] * BLOCK + tid;

    // wave-level lexicographic (dist, idx) butterfly reduction
    #pragma unroll
    for (int r = 0; r < ROWS; ++r) {
        float d = best[r]; int i = kk[r];
        #pragma unroll
        for (int off = 32; off >= 1; off >>= 1) {
            float d2 = __shfl_xor(d, off, 64);
            int   i2 = __shfl_xor(i, off, 64);
            if (d2 < d || (d2 == d && i2 < i)) { d = d2; i = i2; }
        }
        best[r] = d; kk[r] = i;
    }

    int wave = tid >> 6;
    if ((tid & 63) == 0) {
        #pragma unroll
        for (int r = 0; r < ROWS; ++r) {
            sRD[wave * ROWS + r] = best[r];
            sRI[wave * ROWS + r] = kk[r];
        }
    }
    __syncthreads();

    if (tid < ROWS) {
        float d = sRD[tid]; int i = sRI[tid];
        #pragma unroll
        for (int w = 1; w < WAVES; ++w) {
            float d2 = sRD[w * ROWS + tid];
            int   i2 = sRI[w * ROWS + tid];
            if (d2 < d || (d2 == d && i2 < i)) { d = d2; i = i2; }
        }
        out[rowbase + tid] = i;
    }
}

extern "C" void kernel_launch(void* const* d_in, const int* in_sizes, int n_in,
                              void* d_out, int out_size, void* d_ws, size_t ws_size,
                              hipStream_t stream)
{
    const float*  hs = (const float*)d_in[0];    // [1,4,4,48,48]
    const float4* cb = (const float4*)d_in[1];   // [32768,4]
    int* out = (int*)d_out;                      // [9216] int32

    const int nrows = 9216;
    dim3 grid(nrows / ROWS), block(BLOCK);       // 1024 blocks = 4/CU exactly
    vq_argmin_kernel<<<grid, block, 0, stream>>>(hs, cb, out);
}

// Round 7
// 119.525 us; speedup vs baseline: 1.5264x; 1.5264x over previous
//
#include <hip/hip_runtime.h>
#include <cfloat>

// Emu3 VQ-VAE vector quantizer argmin (exact-rounding match to numpy ref):
//   x [9216,4] f32 (channels-last gather from [1,4,4,48,48])
//   e [32768,4] f32
//   out[n] = argmin_k fl( fl(x2+e2) - 2*fl(dot) ), first-min tie semantics.
//
// Round 12 — cut VALU ops/eval on the validated R8 structure:
//  - Occupancy story CLOSED: occ 26/35/47/83% -> 82.5/78.6/82.5/149us.
//    Flat wherever the kernel is intact; R11's (512,8) squeeze spilled
//    (VGPR 32 < ~45 live, 481MB scratch writes). Occupancy is not the lever;
//    neither is prefetch depth (R9) nor SMEM codebook (R10). Only op-count
//    reduction ever helped (R8 -5%).
//  - Change 1: e2 precomputed once in a prep kernel (same fl chain, scheme
//    validated in R10) and loaded as a float stream: -7 VALU/entry
//    (-0.58/eval), +1 small dispatch.
//  - Change 2: min3 pair-update: nb=min3(best,da,db); w=(da<=db)?m1:m2;
//    bidx=(nb<best)?w:bidx  -> 5 ops/pair vs 6. Tie-sound: unchanged best
//    keeps earliest index; da==db picks m1<m2 (first-min exactly).
//  - Distances bitwise unchanged (same mul/fma/fadd/fma chain).
//  - Per-eval VALU ~10.2 -> ~8.8 (-14%). Everything else held at R8 config
//    (ROWS=12, BLOCK=512, grid=768, waves_per_eu(3,4), EPT=2 ping-pong).

#define ROWS  12
#define BLOCK 512
#define WAVES (BLOCK / 64)
#define NROWS 9216
#define NK    32768
#define EPT   2
#define CHUNK (BLOCK * EPT)   // 1024

__device__ __forceinline__ float rlf(float v) {
    return __builtin_bit_cast(float,
        __builtin_amdgcn_readfirstlane(__builtin_bit_cast(int, v)));
}

__global__ __launch_bounds__(256)
void vq_prep(const float4* __restrict__ cb, float* __restrict__ e2t)
{
    int k = blockIdx.x * 256 + threadIdx.x;   // 32768 threads
    float4 e = cb[k];
    e2t[k] = __fadd_rn(__fadd_rn(__fadd_rn(__fmul_rn(e.x, e.x),
                                           __fmul_rn(e.y, e.y)),
                                 __fmul_rn(e.z, e.z)),
                       __fmul_rn(e.w, e.w));
}

__global__ __launch_bounds__(BLOCK)
__attribute__((amdgpu_waves_per_eu(3, 4)))
void vq_argmin_kernel(const float* __restrict__ hs,
                      const float4* __restrict__ cb,
                      const float* __restrict__ e2t,
                      int* __restrict__ out)
{
    __shared__ float sRD[WAVES * ROWS];
    __shared__ int   sRI[WAVES * ROWS];

    const int tid = threadIdx.x;
    const int rowbase = blockIdx.x * ROWS;

    // Block-uniform x components -> readfirstlane into SGPRs.
    float sx0[ROWS], sx1[ROWS], sx2[ROWS], sx3[ROWS], sq[ROWS];
    float best[ROWS];
    int   bidx[ROWS];   // stores chunk index m; k = m*BLOCK + tid

    #pragma unroll
    for (int r = 0; r < ROWS; ++r) {
        int n = rowbase + r;
        int t = n / 2304;                 // 2304 = 48*48
        int rem = n - t * 2304;
        const float* ptr = hs + t * 9216 + rem;   // + c*2304 per channel
        float a0 = ptr[0], a1 = ptr[2304], a2 = ptr[4608], a3 = ptr[6912];
        float q = __fadd_rn(__fadd_rn(__fadd_rn(__fmul_rn(a0, a0),
                                                __fmul_rn(a1, a1)),
                                      __fmul_rn(a2, a2)),
                            __fmul_rn(a3, a3));
        sx0[r] = rlf(a0); sx1[r] = rlf(a1);
        sx2[r] = rlf(a2); sx3[r] = rlf(a3);
        sq[r]  = rlf(q);
        best[r] = FLT_MAX; bidx[r] = 0;
    }

    float4 eA[EPT], eB[EPT];
    float  qA[EPT], qB[EPT];

    auto load_chunk = [&](float4* e, float* q, int tb) {
        #pragma unroll
        for (int j = 0; j < EPT; ++j) {
            e[j] = cb[tb + tid + j * BLOCK];
            q[j] = e2t[tb + tid + j * BLOCK];
        }
    };
    auto compute_chunk = [&](const float4* e, const float* q, int tb) {
        float4 ea = e[0], eb = e[1];
        float  qa = q[0], qb = q[1];
        int m1 = tb / BLOCK;              // uniform chunk indices
        int m2 = m1 + 1;
        #pragma unroll
        for (int r = 0; r < ROWS; ++r) {
            float dota = __fmul_rn(sx0[r], ea.x);
            dota = __fmaf_rn(sx1[r], ea.y, dota);
            dota = __fmaf_rn(sx2[r], ea.z, dota);
            dota = __fmaf_rn(sx3[r], ea.w, dota);
            float ta = __fadd_rn(sq[r], qa);
            float da = __fmaf_rn(dota, -2.0f, ta);

            float dotb = __fmul_rn(sx0[r], eb.x);
            dotb = __fmaf_rn(sx1[r], eb.y, dotb);
            dotb = __fmaf_rn(sx2[r], eb.z, dotb);
            dotb = __fmaf_rn(sx3[r], eb.w, dotb);
            float tb2 = __fadd_rn(sq[r], qb);
            float db = __fmaf_rn(dotb, -2.0f, tb2);

            // min3 pair-update: 5 VALU for 2 evals, first-min tie-exact.
            float nb = fminf(fminf(best[r], da), db);   // -> v_min3_f32
            int   w  = (da <= db) ? m1 : m2;            // pair winner (tie->m1)
            if (nb < best[r]) bidx[r] = w;              // strict < keeps earliest
            best[r] = nb;
        }
    };

    // ---- ping-pong K loop: load one buffer while computing the other
    load_chunk(eA, qA, 0);
    for (int tb = 0; tb < NK; tb += 2 * CHUNK) {
        load_chunk(eB, qB, tb + CHUNK);
        compute_chunk(eA, qA, tb);
        int nb2 = tb + 2 * CHUNK < NK ? tb + 2 * CHUNK : 0;  // last: dummy reload
        load_chunk(eA, qA, nb2);
        compute_chunk(eB, qB, tb + CHUNK);
    }

    // ---- expand chunk index -> full codebook index, then reduce
    int kk[ROWS];
    #pragma unroll
    for (int r = 0; r < ROWS; ++r) kk[r] = bidx[r] * BLOCK + tid;

    // wave-level lexicographic (dist, idx) butterfly reduction
    #pragma unroll
    for (int r = 0; r < ROWS; ++r) {
        float d = best[r]; int i = kk[r];
        #pragma unroll
        for (int off = 32; off >= 1; off >>= 1) {
            float d2 = __shfl_xor(d, off, 64);
            int   i2 = __shfl_xor(i, off, 64);
            if (d2 < d || (d2 == d && i2 < i)) { d = d2; i = i2; }
        }
        best[r] = d; kk[r] = i;
    }

    int wave = tid >> 6;
    if ((tid & 63) == 0) {
        #pragma unroll
        for (int r = 0; r < ROWS; ++r) {
            sRD[wave * ROWS + r] = best[r];
            sRI[wave * ROWS + r] = kk[r];
        }
    }
    __syncthreads();

    if (tid < ROWS) {
        float d = sRD[tid]; int i = sRI[tid];
        #pragma unroll
        for (int w = 1; w < WAVES; ++w) {
            float d2 = sRD[w * ROWS + tid];
            int   i2 = sRI[w * ROWS + tid];
            if (d2 < d || (d2 == d && i2 < i)) { d = d2; i = i2; }
        }
        out[rowbase + tid] = i;
    }
}

extern "C" void kernel_launch(void* const* d_in, const int* in_sizes, int n_in,
                              void* d_out, int out_size, void* d_ws, size_t ws_size,
                              hipStream_t stream)
{
    const float*  hs = (const float*)d_in[0];    // [1,4,4,48,48]
    const float4* cb = (const float4*)d_in[1];   // [32768,4]
    int* out = (int*)d_out;                      // [9216] int32

    float* e2t = (float*)d_ws;                   // 128 KiB in workspace

    vq_prep<<<NK / 256, 256, 0, stream>>>(cb, e2t);

    dim3 grid(NROWS / ROWS), block(BLOCK);       // 768 blocks, R8 config
    vq_argmin_kernel<<<grid, block, 0, stream>>>(hs, cb, e2t, out);
}